// Round 15
// baseline (358.047 us; speedup 1.0000x reference)
//
#include <hip/hip_runtime.h>

// ---------------- bf16 helpers ----------------

__device__ __forceinline__ unsigned short f2bf(float f) {
    unsigned u = __float_as_uint(f);
    unsigned r = (u + 0x7FFFu + ((u >> 16) & 1u)) >> 16;
    return (unsigned short)r;
}
__device__ __forceinline__ float bf2f(unsigned short u) {
    return __uint_as_float(((unsigned)u) << 16);
}

typedef __attribute__((ext_vector_type(8))) short bf16x8;
typedef __attribute__((ext_vector_type(4))) float f32x4;
typedef __attribute__((ext_vector_type(8))) unsigned short u16x8;

// ---------------- node GEMM via MFMA + attention scores ----------------
template<int K, bool IN_BF16>
__global__ __launch_bounds__(256, 4)
void gat_gemm_mfma(const void* __restrict__ Xin, const float* __restrict__ W,
                   const float* __restrict__ a_s, const float* __restrict__ a_d,
                   unsigned short* __restrict__ Hb, float* __restrict__ sc_s,
                   float* __restrict__ sc_d, int nrows) {
    __shared__ unsigned short Xl[64 * K];
    __shared__ unsigned short Wt[K * 64];
    const int t = threadIdx.x;
    const int tile0 = blockIdx.x * 64;
    const int CPR = K / 8;

    for (int c = t; c < 64 * CPR; c += 256) {
        const int row = c / CPR;
        const int ch  = c % CPR;
        const int gr  = tile0 + row;
        u16x8 v;
        if (gr < nrows) {
            if (IN_BF16) {
                v = *reinterpret_cast<const u16x8*>((const unsigned short*)Xin + (size_t)gr * K + ch * 8);
            } else {
                const float* src = (const float*)Xin + (size_t)gr * K + ch * 8;
                const float4 f0 = *reinterpret_cast<const float4*>(src);
                const float4 f1 = *reinterpret_cast<const float4*>(src + 4);
                v[0] = f2bf(f0.x); v[1] = f2bf(f0.y); v[2] = f2bf(f0.z); v[3] = f2bf(f0.w);
                v[4] = f2bf(f1.x); v[5] = f2bf(f1.y); v[6] = f2bf(f1.z); v[7] = f2bf(f1.w);
            }
        } else {
#pragma unroll
            for (int i = 0; i < 8; i++) v[i] = 0;
        }
        *reinterpret_cast<u16x8*>(&Xl[row * K + ((ch * 8) ^ ((row & 7) << 3))]) = v;
    }
    for (int i = t; i < K * 64; i += 256) {
        const int k = i >> 6;
        const int n = i & 63;
        Wt[((k >> 3) * 64 + n) * 8 + (k & 7)] = f2bf(W[i]);
    }
    __syncthreads();

    const int lane = t & 63;
    const int wave = t >> 6;
    const int lg = lane >> 4;
    const int li = lane & 15;

    f32x4 acc[4] = {{0.f,0.f,0.f,0.f},{0.f,0.f,0.f,0.f},{0.f,0.f,0.f,0.f},{0.f,0.f,0.f,0.f}};
    const int r = wave * 16 + li;

#pragma unroll
    for (int s = 0; s < K / 32; s++) {
        const int acol = (s * 32 + lg * 8) ^ ((r & 7) << 3);
        const bf16x8 a = *reinterpret_cast<const bf16x8*>(&Xl[r * K + acol]);
#pragma unroll
        for (int ct = 0; ct < 4; ct++) {
            const bf16x8 b = *reinterpret_cast<const bf16x8*>(&Wt[((s * 4 + lg) * 64 + ct * 16 + li) * 8]);
            acc[ct] = __builtin_amdgcn_mfma_f32_16x16x32_bf16(a, b, acc[ct], 0, 0, 0);
        }
    }

    float asv[4], adv[4];
#pragma unroll
    for (int ct = 0; ct < 4; ct++) {
        asv[ct] = a_s[ct * 16 + li];
        adv[ct] = a_d[ct * 16 + li];
    }
#pragma unroll
    for (int reg = 0; reg < 4; reg++) {
        const int gr = tile0 + wave * 16 + lg * 4 + reg;
        float ps = 0.f, pd = 0.f;
        if (gr < nrows) {
#pragma unroll
            for (int ct = 0; ct < 4; ct++) {
                const float v = acc[ct][reg];
                Hb[(size_t)gr * 64 + ct * 16 + li] = f2bf(v);
                ps += v * asv[ct];
                pd += v * adv[ct];
            }
        }
#pragma unroll
        for (int off = 8; off; off >>= 1) {
            ps += __shfl_xor(ps, off);
            pd += __shfl_xor(pd, off);
        }
        if (li == 0 && gr < nrows) {
            sc_s[gr] = ps;
            sc_d[gr] = pd;
        }
    }
}

// ---------------- CSR build: bucket hist -> bucket scan -> partition -> place
#define BSZ   512
#define NBITS 9
#define CH    4096

__global__ __launch_bounds__(256)
void bucket_hist_kernel(const int* __restrict__ dst, int* __restrict__ bhist, int E) {
    __shared__ int cnt[256];
    const int t = threadIdx.x;
    cnt[t] = 0;
    __syncthreads();
    const int tid = blockIdx.x * blockDim.x + t;
    const int stride = gridDim.x * blockDim.x;
    const int E4 = E >> 2;
    for (int i = tid; i < E4; i += stride) {
        const int4 d = reinterpret_cast<const int4*>(dst)[i];
        atomicAdd(&cnt[d.x >> NBITS], 1);
        atomicAdd(&cnt[d.y >> NBITS], 1);
        atomicAdd(&cnt[d.z >> NBITS], 1);
        atomicAdd(&cnt[d.w >> NBITS], 1);
    }
    for (int i = (E4 << 2) + tid; i < E; i += stride)
        atomicAdd(&cnt[dst[i] >> NBITS], 1);
    __syncthreads();
    if (cnt[t] > 0) atomicAdd(&bhist[t], cnt[t]);
}

__global__ void bucket_scan_kernel(const int* __restrict__ bhist, int* __restrict__ bbase,
                                   int* __restrict__ bcur, int NB, int E) {
    __shared__ int s[256];
    const int t = threadIdx.x;
    const int v = (t < NB) ? bhist[t] : 0;
    s[t] = v;
    __syncthreads();
    for (int off = 1; off < 256; off <<= 1) {
        int u = (t >= off) ? s[t - off] : 0;
        __syncthreads();
        s[t] += u;
        __syncthreads();
    }
    if (t < NB) {
        const int excl = s[t] - v;
        bbase[t] = excl;
        bcur[t] = excl;
    }
    if (t == 0) bbase[NB] = E;
}

__global__ __launch_bounds__(256)
void partition_kernel(const int* __restrict__ ei, int E,
                      int* __restrict__ bcur, unsigned* __restrict__ staged) {
    __shared__ int cnt[256], scantmp[256], excl[256], cnt2[256], gbase[256];
    __shared__ unsigned packed[CH];
    __shared__ unsigned char bid[CH];
    const int t = threadIdx.x;
    const int e0 = blockIdx.x * CH;

    cnt[t] = 0;
    cnt2[t] = 0;
    __syncthreads();

    unsigned pk[16];
    int bb[16];
#pragma unroll
    for (int i = 0; i < 16; i++) {
        const int e = e0 + i * 256 + t;
        if (e < E) {
            const int d = ei[E + e];
            const int s = ei[e];
            bb[i] = d >> NBITS;
            pk[i] = ((unsigned)(d & (BSZ - 1)) << 17) | (unsigned)s;
            atomicAdd(&cnt[bb[i]], 1);
        } else bb[i] = -1;
    }
    __syncthreads();

    int v = cnt[t];
    scantmp[t] = v;
    __syncthreads();
    for (int off = 1; off < 256; off <<= 1) {
        int u = (t >= off) ? scantmp[t - off] : 0;
        __syncthreads();
        scantmp[t] += u;
        __syncthreads();
    }
    excl[t] = scantmp[t] - v;
    if (v > 0) gbase[t] = atomicAdd(&bcur[t], v);
    __syncthreads();

#pragma unroll
    for (int i = 0; i < 16; i++) {
        if (bb[i] >= 0) {
            const int slot = atomicAdd(&cnt2[bb[i]], 1);
            const int p = excl[bb[i]] + slot;
            packed[p] = pk[i];
            bid[p] = (unsigned char)bb[i];
        }
    }
    __syncthreads();

    const int nvalid = min(CH, E - e0);
    for (int i = t; i < nvalid; i += 256) {
        const int b = bid[i];
        staged[gbase[b] + (i - excl[b])] = packed[i];
    }
}

__global__ __launch_bounds__(256)
void place_kernel(const unsigned* __restrict__ staged, const int* __restrict__ bbase,
                  int* __restrict__ rowptr, int* __restrict__ col, int N, int E, int NB) {
    __shared__ int nc[BSZ];
    __shared__ int rp[BSZ];
    __shared__ int pairs[256];
    const int b = blockIdx.x;
    const int n0 = b * BSZ;
    const int nn = min(BSZ, N - n0);
    const int t = threadIdx.x;

    nc[t] = 0;
    nc[t + 256] = 0;
    __syncthreads();

    const int lo = bbase[b];
    const int hi = bbase[b + 1];
    for (int e = lo + t; e < hi; e += 256)
        atomicAdd(&nc[staged[e] >> 17], 1);
    __syncthreads();

    const int c0 = nc[2 * t], c1 = nc[2 * t + 1];
    const int ps = c0 + c1;
    pairs[t] = ps;
    __syncthreads();
    for (int off = 1; off < 256; off <<= 1) {
        int u = (t >= off) ? pairs[t - off] : 0;
        __syncthreads();
        pairs[t] += u;
        __syncthreads();
    }
    const int pexcl = pairs[t] - ps;
    rp[2 * t]     = lo + pexcl;
    rp[2 * t + 1] = lo + pexcl + c0;
    nc[2 * t] = 0;
    nc[2 * t + 1] = 0;
    __syncthreads();

    for (int i = t; i < nn; i += 256) rowptr[n0 + i] = rp[i];
    if (b == NB - 1 && t == 0) rowptr[N] = E;

    for (int e = lo + t; e < hi; e += 256) {
        const unsigned p = staged[e];
        const int dlo = (int)(p >> 17);
        const int src = (int)(p & 0x1FFFFu);
        const int pos = rp[dlo] + atomicAdd(&nc[dlo], 1);
        col[pos] = src;
    }
}

// ---------------- fused per-node online-softmax aggregation ------------------
// Wave-parallel softmax; TWO nodes per wave. Phase-2 streams of both nodes are
// MERGED into one loop (8 outstanding broadcast row-loads in the common prefix)
// -> double memory-level parallelism at unchanged live state.
template<bool RELU, bool OUTBF>
__global__ void gat_fused_agg(const int* __restrict__ rowptr, const int* __restrict__ col,
                              const float* __restrict__ sc_s, const float* __restrict__ sc_d,
                              const unsigned short* __restrict__ Hb, const float* __restrict__ bias,
                              void* __restrict__ Out, int N) {
    const int lane = threadIdx.x & 63;
    int gw = (blockIdx.x * blockDim.x + threadIdx.x) >> 6;
    const int nw = (gridDim.x * blockDim.x) >> 6;
    const float bl = bias[lane];
    const char* hbl = (const char*)Hb + lane * 2;
    const int npairs = (N + 1) >> 1;

    for (int p = gw; p < npairs; p += nw) {
        const int i0 = 2 * p;
        const int i1 = 2 * p + 1;
        const bool has1 = (i1 < N);

        const float scd0 = sc_d[i0];
        float es0 = sc_s[i0] + scd0;
        es0 = es0 > 0.f ? es0 : 0.2f * es0;
        float m0 = es0, denom0 = 1.f;
        float acc0 = bf2f(Hb[(size_t)i0 * 64 + lane]);
        int j0 = rowptr[i0];
        const int je0 = rowptr[i0 + 1];

        float scd1 = 0.f, m1 = 0.f, denom1 = 1.f, acc1 = 0.f;
        int j1 = 0, je1 = 0;
        if (has1) {
            scd1 = sc_d[i1];
            float es1 = sc_s[i1] + scd1;
            es1 = es1 > 0.f ? es1 : 0.2f * es1;
            m1 = es1;
            acc1 = bf2f(Hb[(size_t)i1 * 64 + lane]);
            j1 = rowptr[i1];
            je1 = rowptr[i1 + 1];
        }

        while (j0 < je0 || j1 < je1) {
            // ---- phase 1: issue BOTH nodes' per-lane gathers ----
            int nj0 = 0, nj1 = 0;
            int soff0 = 0, soff1 = 0;
            float el0 = -1e30f, el1 = -1e30f;
            if (j0 < je0) {
                nj0 = min(64, je0 - j0);
                if (lane < nj0) {
                    const int sl = col[j0 + lane];
                    soff0 = sl << 7;
                    const float ev = sc_s[sl] + scd0;
                    el0 = ev > 0.f ? ev : 0.2f * ev;
                }
            }
            if (j1 < je1) {
                nj1 = min(64, je1 - j1);
                if (lane < nj1) {
                    const int sl = col[j1 + lane];
                    soff1 = sl << 7;
                    const float ev = sc_s[sl] + scd1;
                    el1 = ev > 0.f ? ev : 0.2f * ev;
                }
            }
            // ---- softmax scalars ----
            float wl0 = 0.f, wl1 = 0.f;
            if (nj0) {
                float cm = el0;
#pragma unroll
                for (int off = 32; off; off >>= 1) cm = fmaxf(cm, __shfl_xor(cm, off));
                const float mn = fmaxf(m0, cm);
                wl0 = (lane < nj0) ? __expf(el0 - mn) : 0.f;
                float wsum = wl0;
#pragma unroll
                for (int off = 32; off; off >>= 1) wsum += __shfl_xor(wsum, off);
                const float scale = __expf(m0 - mn);
                denom0 = denom0 * scale + wsum;
                acc0 *= scale;
                m0 = mn;
            }
            if (nj1) {
                float cm = el1;
#pragma unroll
                for (int off = 32; off; off >>= 1) cm = fmaxf(cm, __shfl_xor(cm, off));
                const float mn = fmaxf(m1, cm);
                wl1 = (lane < nj1) ? __expf(el1 - mn) : 0.f;
                float wsum = wl1;
#pragma unroll
                for (int off = 32; off; off >>= 1) wsum += __shfl_xor(wsum, off);
                const float scale = __expf(m1 - mn);
                denom1 = denom1 * scale + wsum;
                acc1 *= scale;
                m1 = mn;
            }
            // ---- phase 2: MERGED broadcast-accumulate (8 loads in flight) ----
            const int wb0 = __float_as_int(wl0);
            const int wb1 = __float_as_int(wl1);
            float A0 = 0.f, A1 = 0.f, A2 = 0.f, A3 = 0.f;
            float B0 = 0.f, B1 = 0.f, B2 = 0.f, B3 = 0.f;
            const int njc = min(nj0, nj1);
            int qm = 0;
            for (; qm + 4 <= njc; qm += 4) {
                const int o00 = __builtin_amdgcn_readlane(soff0, qm);
                const int o01 = __builtin_amdgcn_readlane(soff0, qm + 1);
                const int o02 = __builtin_amdgcn_readlane(soff0, qm + 2);
                const int o03 = __builtin_amdgcn_readlane(soff0, qm + 3);
                const int o10 = __builtin_amdgcn_readlane(soff1, qm);
                const int o11 = __builtin_amdgcn_readlane(soff1, qm + 1);
                const int o12 = __builtin_amdgcn_readlane(soff1, qm + 2);
                const int o13 = __builtin_amdgcn_readlane(soff1, qm + 3);
                const unsigned short h00 = *(const unsigned short*)(hbl + o00);
                const unsigned short h01 = *(const unsigned short*)(hbl + o01);
                const unsigned short h02 = *(const unsigned short*)(hbl + o02);
                const unsigned short h03 = *(const unsigned short*)(hbl + o03);
                const unsigned short h10 = *(const unsigned short*)(hbl + o10);
                const unsigned short h11 = *(const unsigned short*)(hbl + o11);
                const unsigned short h12 = *(const unsigned short*)(hbl + o12);
                const unsigned short h13 = *(const unsigned short*)(hbl + o13);
                const float w00 = __int_as_float(__builtin_amdgcn_readlane(wb0, qm));
                const float w01 = __int_as_float(__builtin_amdgcn_readlane(wb0, qm + 1));
                const float w02 = __int_as_float(__builtin_amdgcn_readlane(wb0, qm + 2));
                const float w03 = __int_as_float(__builtin_amdgcn_readlane(wb0, qm + 3));
                const float w10 = __int_as_float(__builtin_amdgcn_readlane(wb1, qm));
                const float w11 = __int_as_float(__builtin_amdgcn_readlane(wb1, qm + 1));
                const float w12 = __int_as_float(__builtin_amdgcn_readlane(wb1, qm + 2));
                const float w13 = __int_as_float(__builtin_amdgcn_readlane(wb1, qm + 3));
                A0 += w00 * bf2f(h00);
                A1 += w01 * bf2f(h01);
                A2 += w02 * bf2f(h02);
                A3 += w03 * bf2f(h03);
                B0 += w10 * bf2f(h10);
                B1 += w11 * bf2f(h11);
                B2 += w12 * bf2f(h12);
                B3 += w13 * bf2f(h13);
            }
            // node0 tail (4-deep, then scalar)
            int q0 = qm;
            for (; q0 + 4 <= nj0; q0 += 4) {
                const int o0 = __builtin_amdgcn_readlane(soff0, q0);
                const int o1 = __builtin_amdgcn_readlane(soff0, q0 + 1);
                const int o2 = __builtin_amdgcn_readlane(soff0, q0 + 2);
                const int o3 = __builtin_amdgcn_readlane(soff0, q0 + 3);
                const unsigned short h0 = *(const unsigned short*)(hbl + o0);
                const unsigned short h1 = *(const unsigned short*)(hbl + o1);
                const unsigned short h2 = *(const unsigned short*)(hbl + o2);
                const unsigned short h3 = *(const unsigned short*)(hbl + o3);
                const float w0 = __int_as_float(__builtin_amdgcn_readlane(wb0, q0));
                const float w1 = __int_as_float(__builtin_amdgcn_readlane(wb0, q0 + 1));
                const float w2 = __int_as_float(__builtin_amdgcn_readlane(wb0, q0 + 2));
                const float w3 = __int_as_float(__builtin_amdgcn_readlane(wb0, q0 + 3));
                A0 += w0 * bf2f(h0);
                A1 += w1 * bf2f(h1);
                A2 += w2 * bf2f(h2);
                A3 += w3 * bf2f(h3);
            }
            for (; q0 < nj0; q0++) {
                const int o0 = __builtin_amdgcn_readlane(soff0, q0);
                const float w0 = __int_as_float(__builtin_amdgcn_readlane(wb0, q0));
                A0 += w0 * bf2f(*(const unsigned short*)(hbl + o0));
            }
            // node1 tail
            int q1 = qm;
            for (; q1 + 4 <= nj1; q1 += 4) {
                const int o0 = __builtin_amdgcn_readlane(soff1, q1);
                const int o1 = __builtin_amdgcn_readlane(soff1, q1 + 1);
                const int o2 = __builtin_amdgcn_readlane(soff1, q1 + 2);
                const int o3 = __builtin_amdgcn_readlane(soff1, q1 + 3);
                const unsigned short h0 = *(const unsigned short*)(hbl + o0);
                const unsigned short h1 = *(const unsigned short*)(hbl + o1);
                const unsigned short h2 = *(const unsigned short*)(hbl + o2);
                const unsigned short h3 = *(const unsigned short*)(hbl + o3);
                const float w0 = __int_as_float(__builtin_amdgcn_readlane(wb1, q1));
                const float w1 = __int_as_float(__builtin_amdgcn_readlane(wb1, q1 + 1));
                const float w2 = __int_as_float(__builtin_amdgcn_readlane(wb1, q1 + 2));
                const float w3 = __int_as_float(__builtin_amdgcn_readlane(wb1, q1 + 3));
                B0 += w0 * bf2f(h0);
                B1 += w1 * bf2f(h1);
                B2 += w2 * bf2f(h2);
                B3 += w3 * bf2f(h3);
            }
            for (; q1 < nj1; q1++) {
                const int o0 = __builtin_amdgcn_readlane(soff1, q1);
                const float w0 = __int_as_float(__builtin_amdgcn_readlane(wb1, q1));
                B0 += w0 * bf2f(*(const unsigned short*)(hbl + o0));
            }
            if (nj0) {
                acc0 += (A0 + A1) + (A2 + A3);
                j0 += 64;
            }
            if (nj1) {
                acc1 += (B0 + B1) + (B2 + B3);
                j1 += 64;
            }
        }

        {
            float o = acc0 / denom0 + bl;
            if (RELU) o = o > 0.f ? o : 0.f;
            if (OUTBF) ((unsigned short*)Out)[(size_t)i0 * 64 + lane] = f2bf(o);
            else       ((float*)Out)[(size_t)i0 * 64 + lane] = o;
        }
        if (has1) {
            float o = acc1 / denom1 + bl;
            if (RELU) o = o > 0.f ? o : 0.f;
            if (OUTBF) ((unsigned short*)Out)[(size_t)i1 * 64 + lane] = f2bf(o);
            else       ((float*)Out)[(size_t)i1 * 64 + lane] = o;
        }
    }
}

// ---------------- pooling (batch sorted; small chunks, many waves) ----------------

__global__ void pool_kernel(const float* __restrict__ H, const int* __restrict__ batch,
                            float* __restrict__ sums, int* __restrict__ cnts, int N) {
    const int CHUNK = 32;
    const int lane = threadIdx.x & 63;
    int gw = (blockIdx.x * blockDim.x + threadIdx.x) >> 6;
    const int nw = (gridDim.x * blockDim.x) >> 6;
    const int nchunks = (N + CHUNK - 1) / CHUNK;
    for (int c = gw; c < nchunks; c += nw) {
        const int lo = c * CHUNK;
        const int hi = min(lo + CHUNK, N);
        int curb = batch[lo];
        float acc = 0.f;
        int cnt = 0;
        for (int n = lo; n < hi; n++) {
            int b = batch[n];
            if (b != curb) {
                unsafeAtomicAdd(&sums[(size_t)curb * 64 + lane], acc);
                if (lane == 0) atomicAdd(&cnts[curb], cnt);
                acc = 0.f; cnt = 0; curb = b;
            }
            acc += H[(size_t)n * 64 + lane];
            cnt++;
        }
        unsafeAtomicAdd(&sums[(size_t)curb * 64 + lane], acc);
        if (lane == 0) atomicAdd(&cnts[curb], cnt);
    }
}

// ---------------- final MLP + log_softmax ----------------
__global__ void mlp_kernel(const float* __restrict__ sums, const int* __restrict__ cnts,
                           const float* __restrict__ lw, const float* __restrict__ lb,
                           const float* __restrict__ cw, const float* __restrict__ cb,
                           float* __restrict__ out) {
    __shared__ float gv[64];
    __shared__ float z[32];
    __shared__ float logits[6];
    const int g = blockIdx.x;
    const int t = threadIdx.x;

    float cnt = (float)cnts[g];
    cnt = cnt > 1.f ? cnt : 1.f;
    gv[t] = sums[(size_t)g * 64 + t] / cnt;
    __syncthreads();

    if (t < 32) {
        float acc = lb[t];
#pragma unroll
        for (int k = 0; k < 64; k++) acc += gv[k] * lw[k * 32 + t];
        z[t] = acc > 0.f ? acc : 0.f;
    }
    __syncthreads();
    if (t < 6) {
        float acc = cb[t];
#pragma unroll
        for (int k = 0; k < 32; k++) acc += z[k] * cw[k * 6 + t];
        logits[t] = acc;
    }
    __syncthreads();
    if (t == 0) {
        float m = logits[0];
#pragma unroll
        for (int i = 1; i < 6; i++) m = fmaxf(m, logits[i]);
        float s = 0.f;
#pragma unroll
        for (int i = 0; i < 6; i++) s += expf(logits[i] - m);
        float lse = m + logf(s);
#pragma unroll
        for (int i = 0; i < 6; i++) out[(size_t)g * 6 + i] = logits[i] - lse;
    }
}

// ---------------- launch ----------------

extern "C" void kernel_launch(void* const* d_in, const int* in_sizes, int n_in,
                              void* d_out, int out_size, void* d_ws, size_t ws_size,
                              hipStream_t stream) {
    const float* x    = (const float*)d_in[0];
    const int*   ei   = (const int*)d_in[1];
    const int*   batch= (const int*)d_in[2];
    const float* W1   = (const float*)d_in[3];
    const float* as1  = (const float*)d_in[4];
    const float* ad1  = (const float*)d_in[5];
    const float* b1   = (const float*)d_in[6];
    const float* W2   = (const float*)d_in[7];
    const float* as2  = (const float*)d_in[8];
    const float* ad2  = (const float*)d_in[9];
    const float* b2   = (const float*)d_in[10];
    const float* lw   = (const float*)d_in[11];
    const float* lb   = (const float*)d_in[12];
    const float* cw   = (const float*)d_in[13];
    const float* cb   = (const float*)d_in[14];
    float* out = (float*)d_out;

    const int N  = in_sizes[0] / 128;
    const int E  = in_sizes[1] / 2;
    const int G  = out_size / 6;
    const int NB = (N + BSZ - 1) / BSZ;

    char* ws = (char*)d_ws;
    size_t off = 0;
    auto alloc = [&](size_t bytes) {
        void* p = ws + off;
        off += (bytes + 255) & ~size_t(255);
        return p;
    };
    float*          hB     = (float*)alloc((size_t)N * 64 * 4);
    unsigned short* hB1b   = (unsigned short*)alloc((size_t)N * 64 * 2);
    unsigned short* Hb     = (unsigned short*)alloc((size_t)N * 64 * 2);
    float*          sc_s   = (float*)alloc((size_t)N * 4);
    float*          sc_d   = (float*)alloc((size_t)N * 4);
    int*            rowptr = (int*)alloc((size_t)(N + 1) * 4);
    int*            colidx = (int*)alloc((size_t)E * 4);
    unsigned*       staged = (unsigned*)alloc((size_t)E * 4);
    int*            bhist  = (int*)alloc((size_t)256 * 4);
    int*            bbase  = (int*)alloc((size_t)257 * 4);
    int*            bcur   = (int*)alloc((size_t)256 * 4);
    float*          psum   = (float*)alloc((size_t)G * 64 * 4);
    int*            pcnt   = (int*)alloc((size_t)G * 4);
    (void)ws_size;

    const int TB = 256;
    const int gemm_grid = (N + 63) / 64;
    const int part_blocks = (E + CH - 1) / CH;

    // ---- CSR build by dst ----
    hipMemsetAsync(bhist, 0, 256 * 4, stream);
    bucket_hist_kernel<<<1024, TB, 0, stream>>>(ei + E, bhist, E);
    bucket_scan_kernel<<<1, 256, 0, stream>>>(bhist, bbase, bcur, NB, E);
    partition_kernel<<<part_blocks, 256, 0, stream>>>(ei, E, bcur, staged);
    place_kernel<<<NB, 256, 0, stream>>>(staged, bbase, rowptr, colidx, N, E, NB);

    // ---- layer 1 ----
    gat_gemm_mfma<128, false><<<gemm_grid, TB, 0, stream>>>(x, W1, as1, ad1, Hb, sc_s, sc_d, N);
    gat_fused_agg<true, true><<<2048, TB, 0, stream>>>(rowptr, colidx, sc_s, sc_d, Hb, b1, hB1b, N);

    // ---- layer 2 ----
    gat_gemm_mfma<64, true><<<gemm_grid, TB, 0, stream>>>(hB1b, W2, as2, ad2, Hb, sc_s, sc_d, N);
    gat_fused_agg<false, false><<<2048, TB, 0, stream>>>(rowptr, colidx, sc_s, sc_d, Hb, b2, hB, N);

    // ---- pooling + MLP head ----
    hipMemsetAsync(psum, 0, (size_t)G * 64 * 4, stream);
    hipMemsetAsync(pcnt, 0, (size_t)G * 4, stream);
    pool_kernel<<<1024, TB, 0, stream>>>(hB, batch, psum, pcnt, N);
    mlp_kernel<<<G, 64, 0, stream>>>(psum, pcnt, lw, lb, cw, cb, out);
}